// Round 1
// baseline (1620.036 us; speedup 1.0000x reference)
//
#include <hip/hip_runtime.h>

// Problem constants (CausalSelfAttention: B=4 T=2048 C=768 H=KVH=6 D=128)
#define BB 4
#define TT 2048
#define CC 768
#define HH 6
#define DD 128
#define BT (BB * TT)          // 8192 rows
#define HALF 64

typedef __bf16 v8bf __attribute__((ext_vector_type(8)));
typedef float f32x4 __attribute__((ext_vector_type(4)));

// ---------------- fp32 -> bf16 (RNE) ----------------
__device__ __forceinline__ unsigned short f2b(float f) {
  union { float f; unsigned u; } v; v.f = f;
  unsigned r = v.u + 0x7FFFu + ((v.u >> 16) & 1u);
  return (unsigned short)(r >> 16);
}

__global__ __launch_bounds__(256) void cvt_f2b_kernel(const float* __restrict__ src,
                                                      unsigned short* __restrict__ dst,
                                                      int n4) {
  int i = blockIdx.x * 256 + threadIdx.x;
  if (i >= n4) return;
  float4 f = ((const float4*)src)[i];
  ushort4 o;
  o.x = f2b(f.x); o.y = f2b(f.y); o.z = f2b(f.z); o.w = f2b(f.w);
  ((ushort4*)dst)[i] = o;
}

// ---------------- bf16 MFMA GEMM: C[M,N] = A[M,K] * W[N,K]^T ----------------
// A row-major (M,K) bf16, W row-major (N,K) bf16 (PyTorch-style weight), C fp32.
// 64x64 tile, BK=32, 256 threads = 4 waves; wave w owns rows [w*16, w*16+16),
// 4 n-tiles of 16. mfma_f32_16x16x32_bf16 fragment maps (HW-verified, guide §3):
//   A/B: lane holds [m|n = lane&15][k = (lane>>4)*8 + j]  (8 bf16 = 16B)
//   C/D: col = lane&15, row = (lane>>4)*4 + reg
__global__ __launch_bounds__(256) void gemm_bf16(const unsigned short* __restrict__ A,
                                                 const unsigned short* __restrict__ W,
                                                 float* __restrict__ C,
                                                 int M, int N, int K) {
  __shared__ __align__(16) unsigned short As[64][32];
  __shared__ __align__(16) unsigned short Bs[64][32];
  const int m0 = blockIdx.x * 64, n0 = blockIdx.y * 64;
  const int t = threadIdx.x;
  const int wave = t >> 6, lane = t & 63;
  const int fr = lane & 15, quad = lane >> 4, k0 = quad * 8;
  const int srow = t >> 2, scol = (t & 3) * 8;   // staging: 16B per thread per tile

  f32x4 acc[4];
#pragma unroll
  for (int i = 0; i < 4; i++) acc[i] = (f32x4){0.f, 0.f, 0.f, 0.f};

  const unsigned short* Arow = A + (size_t)(m0 + srow) * K + scol;
  const unsigned short* Wrow = W + (size_t)(n0 + srow) * K + scol;

  for (int kk = 0; kk < K; kk += 32) {
    *(uint4*)&As[srow][scol] = *(const uint4*)(Arow + kk);
    *(uint4*)&Bs[srow][scol] = *(const uint4*)(Wrow + kk);
    __syncthreads();
    v8bf a = *(const v8bf*)&As[wave * 16 + fr][k0];
#pragma unroll
    for (int nt = 0; nt < 4; nt++) {
      v8bf b = *(const v8bf*)&Bs[nt * 16 + fr][k0];
      acc[nt] = __builtin_amdgcn_mfma_f32_16x16x32_bf16(a, b, acc[nt], 0, 0, 0);
    }
    __syncthreads();
  }

  const int orow = m0 + wave * 16 + quad * 4;
#pragma unroll
  for (int nt = 0; nt < 4; nt++) {
    int oc = n0 + nt * 16 + fr;
#pragma unroll
    for (int rr = 0; rr < 4; rr++)
      C[(size_t)(orow + rr) * N + oc] = acc[nt][rr];
  }
}

// ---------------- RoPE + sample-var norm, in place on q or k ----------------
// One wave per (b,t,h) vector of 128: lane i holds pair (d=i, d=i+64).
// ref: x1=t[:64], x2=t[64:]; out = [x1*c + x2*s, -x1*s + x2*c]; then
// (x-mean)/(sqrt(sum((x-mean)^2)/127) + 1e-6)
__global__ __launch_bounds__(256) void rope_norm_kernel(float* __restrict__ qk,
                                                        const float* __restrict__ cosb,
                                                        const float* __restrict__ sinb) {
  int idx = blockIdx.x * 4 + (threadIdx.x >> 6);   // (b*T + t)*H + h
  int lane = threadIdx.x & 63;
  int h = idx % HH;
  int bt = idx / HH;
  int tpos = bt & (TT - 1);
  size_t base = (size_t)bt * CC + h * DD;

  float x1 = qk[base + lane];
  float x2 = qk[base + HALF + lane];
  float c = cosb[tpos * HALF + lane];
  float s = sinb[tpos * HALF + lane];
  float o1 = x1 * c + x2 * s;
  float o2 = x2 * c - x1 * s;

  float sum = o1 + o2;
#pragma unroll
  for (int off = 32; off; off >>= 1) sum += __shfl_xor(sum, off);
  float mean = sum * (1.f / 128.f);
  float d1 = o1 - mean, d2 = o2 - mean;
  float vs = d1 * d1 + d2 * d2;
#pragma unroll
  for (int off = 32; off; off >>= 1) vs += __shfl_xor(vs, off);
  float inv = 1.f / (sqrtf(vs * (1.f / 127.f)) + 1e-6f);
  qk[base + lane] = d1 * inv;
  qk[base + HALF + lane] = d2 * inv;
}

// ---------------- scalar fp32 flash attention (causal) ----------------
// grid = (T/32, B*H). Block: 256 threads; Q-tile 32 rows x 128; K/V tiles 32 rows.
// Thread t: r = t>>3 (q-row), g = t&7; owns score cols {g + 8*jj} and O cols
// {g*4 + 32*i + u}. LDS padded to 132 floats/row (bank-conflict-free patterns).
// Heavy-first qt order so the long-diagonal blocks launch first.
__global__ __launch_bounds__(256) void attn_fp32(const float* __restrict__ q,
                                                 const float* __restrict__ k,
                                                 const float* __restrict__ v,
                                                 float* __restrict__ y) {
  __shared__ __align__(16) float Qs[32][132];
  __shared__ __align__(16) float Ks[32][132];
  __shared__ __align__(16) float Vs[32][132];
  __shared__ float Ps[32][33];

  const int qt = gridDim.x - 1 - blockIdx.x;      // heavy tiles first
  const int bh = blockIdx.y;
  const int b = bh / HH, h = bh % HH;
  const int t = threadIdx.x;
  const int r = t >> 3, g = t & 7;
  const size_t base_bh = (size_t)b * TT * CC + (size_t)h * DD;

  // load Q tile (32x128): 4 x (256 threads x float4), coalesced
#pragma unroll
  for (int e = 0; e < 4; e++) {
    int idx = (e * 256 + t) * 4;
    int row = idx >> 7, col = idx & 127;
    *(float4*)&Qs[row][col] = *(const float4*)&q[base_bh + (size_t)(qt * 32 + row) * CC + col];
  }

  float o_acc[16];
#pragma unroll
  for (int i = 0; i < 16; i++) o_acc[i] = 0.f;
  float m_i = -1e30f, l_i = 0.f;
  const int qrow = qt * 32 + r;
  const int ntiles = qt + 1;

  for (int jt = 0; jt < ntiles; jt++) {
    const int j0 = jt * 32;
    __syncthreads();   // protect Ks/Vs/Ps from previous iteration readers (also covers Qs on jt=0)
#pragma unroll
    for (int e = 0; e < 4; e++) {
      int idx = (e * 256 + t) * 4;
      int row = idx >> 7, col = idx & 127;
      *(float4*)&Ks[row][col] = *(const float4*)&k[base_bh + (size_t)(j0 + row) * CC + col];
      *(float4*)&Vs[row][col] = *(const float4*)&v[base_bh + (size_t)(j0 + row) * CC + col];
    }
    __syncthreads();

    // S[r][g+8*jj] = Q[r]·K[g+8*jj] * scale
    float s[4] = {0.f, 0.f, 0.f, 0.f};
    for (int d4 = 0; d4 < 32; d4++) {
      float4 q4 = *(const float4*)&Qs[r][d4 * 4];
#pragma unroll
      for (int jj = 0; jj < 4; jj++) {
        float4 k4 = *(const float4*)&Ks[g + 8 * jj][d4 * 4];
        s[jj] += q4.x * k4.x + q4.y * k4.y + q4.z * k4.z + q4.w * k4.w;
      }
    }
    float mloc = -1e30f;
#pragma unroll
    for (int jj = 0; jj < 4; jj++) {
      s[jj] *= 0.08838834764831845f;                 // 1/sqrt(128)
      if (j0 + g + 8 * jj > qrow) s[jj] = -1e30f;    // causal mask
      mloc = fmaxf(mloc, s[jj]);
    }
    // row reduce across the 8 consecutive lanes owning row r
    mloc = fmaxf(mloc, __shfl_xor(mloc, 1));
    mloc = fmaxf(mloc, __shfl_xor(mloc, 2));
    mloc = fmaxf(mloc, __shfl_xor(mloc, 4));
    float m_new = fmaxf(m_i, mloc);
    float alpha = __expf(m_i - m_new);
    float psum = 0.f;
#pragma unroll
    for (int jj = 0; jj < 4; jj++) {
      float p = __expf(s[jj] - m_new);
      Ps[r][g + 8 * jj] = p;
      psum += p;
    }
    psum += __shfl_xor(psum, 1);
    psum += __shfl_xor(psum, 2);
    psum += __shfl_xor(psum, 4);
    l_i = alpha * l_i + psum;
    m_i = m_new;
#pragma unroll
    for (int i = 0; i < 16; i++) o_acc[i] *= alpha;
    __syncthreads();   // Ps visible

    // O[r][g*4 + 32*i] += P[r][:] · V[:][...]
    for (int j = 0; j < 32; j++) {
      float p = Ps[r][j];
#pragma unroll
      for (int i = 0; i < 4; i++) {
        float4 v4 = *(const float4*)&Vs[j][g * 4 + 32 * i];
        o_acc[i * 4 + 0] += p * v4.x;
        o_acc[i * 4 + 1] += p * v4.y;
        o_acc[i * 4 + 2] += p * v4.z;
        o_acc[i * 4 + 3] += p * v4.w;
      }
    }
  }

  float inv_l = 1.f / l_i;
  size_t orow = ((size_t)b * TT + qt * 32 + r) * CC + h * DD;
#pragma unroll
  for (int i = 0; i < 4; i++) {
    float4 o4 = {o_acc[i * 4 + 0] * inv_l, o_acc[i * 4 + 1] * inv_l,
                 o_acc[i * 4 + 2] * inv_l, o_acc[i * 4 + 3] * inv_l};
    *(float4*)&y[orow + g * 4 + 32 * i] = o4;
  }
}

// ---------------- launch ----------------
extern "C" void kernel_launch(void* const* d_in, const int* in_sizes, int n_in,
                              void* d_out, int out_size, void* d_ws, size_t ws_size,
                              hipStream_t stream) {
  const float* x     = (const float*)d_in[0];
  const float* cosb  = (const float*)d_in[1];
  const float* sinb  = (const float*)d_in[2];
  const float* wq    = (const float*)d_in[3];
  const float* wk    = (const float*)d_in[4];
  const float* wv    = (const float*)d_in[5];
  const float* wproj = (const float*)d_in[6];
  float* out = (float*)d_out;

  // workspace layout (bytes): q,k,v,y fp32 (25.17 MB each) + bf16 area (~17.3 MB)
  char* w = (char*)d_ws;
  float* q = (float*)(w);
  float* kk = (float*)(w + 25165824);
  float* v = (float*)(w + 50331648);
  float* y = (float*)(w + 75497472);
  unsigned short* xb  = (unsigned short*)(w + 100663296);  // reused as yb later
  unsigned short* wqb = (unsigned short*)(w + 113246208);
  unsigned short* wkb = (unsigned short*)(w + 114425856);
  unsigned short* wvb = (unsigned short*)(w + 115605504);
  unsigned short* wpb = (unsigned short*)(w + 116785152);
  // total: 117,964,800 bytes

  const int nx4 = BT * CC / 4;       // 1572864
  const int nw4 = CC * CC / 4;       // 147456

  // convert inputs to bf16
  cvt_f2b_kernel<<<(nx4 + 255) / 256, 256, 0, stream>>>(x, xb, nx4);
  cvt_f2b_kernel<<<(nw4 + 255) / 256, 256, 0, stream>>>(wq, wqb, nw4);
  cvt_f2b_kernel<<<(nw4 + 255) / 256, 256, 0, stream>>>(wk, wkb, nw4);
  cvt_f2b_kernel<<<(nw4 + 255) / 256, 256, 0, stream>>>(wv, wvb, nw4);
  cvt_f2b_kernel<<<(nw4 + 255) / 256, 256, 0, stream>>>(wproj, wpb, nw4);

  // QKV projections: (8192x768) = xb(8192x768) * w(768x768)^T
  dim3 ggrid(BT / 64, CC / 64);
  gemm_bf16<<<ggrid, 256, 0, stream>>>(xb, wqb, q, BT, CC, CC);
  gemm_bf16<<<ggrid, 256, 0, stream>>>(xb, wkb, kk, BT, CC, CC);
  gemm_bf16<<<ggrid, 256, 0, stream>>>(xb, wvb, v, BT, CC, CC);

  // RoPE + norm on q and k (one wave per (b,t,h) vector)
  int nvec = BT * HH;  // 49152
  rope_norm_kernel<<<nvec / 4, 256, 0, stream>>>(q, cosb, sinb);
  rope_norm_kernel<<<nvec / 4, 256, 0, stream>>>(kk, cosb, sinb);

  // causal flash attention -> y in (b, t, h*D+d) layout
  attn_fp32<<<dim3(TT / 32, BB * HH), 256, 0, stream>>>(q, kk, v, y);

  // output projection: out = y * wproj^T
  cvt_f2b_kernel<<<(nx4 + 255) / 256, 256, 0, stream>>>(y, xb, nx4);
  gemm_bf16<<<ggrid, 256, 0, stream>>>(xb, wpb, out, BT, CC, CC);
}

// Round 2
// 361.544 us; speedup vs baseline: 4.4809x; 4.4809x over previous
//
#include <hip/hip_runtime.h>

// Problem constants (CausalSelfAttention: B=4 T=2048 C=768 H=KVH=6 D=128)
#define BB 4
#define TT 2048
#define CC 768
#define HH 6
#define DD 128
#define BT (BB * TT)          // 8192 rows
#define HALF 64
#define SCALE 0.08838834764831845f   // 1/sqrt(128)

typedef __bf16 v8bf __attribute__((ext_vector_type(8)));
typedef float f32x4 __attribute__((ext_vector_type(4)));

// ---------------- fp32 -> bf16 (RNE) ----------------
__device__ __forceinline__ unsigned short f2b(float f) {
  union { float f; unsigned u; } v; v.f = f;
  unsigned r = v.u + 0x7FFFu + ((v.u >> 16) & 1u);
  return (unsigned short)(r >> 16);
}

__global__ __launch_bounds__(256) void cvt_f2b_kernel(const float* __restrict__ src,
                                                      unsigned short* __restrict__ dst,
                                                      int n4) {
  int i = blockIdx.x * 256 + threadIdx.x;
  if (i >= n4) return;
  float4 f = ((const float4*)src)[i];
  ushort4 o;
  o.x = f2b(f.x); o.y = f2b(f.y); o.z = f2b(f.z); o.w = f2b(f.w);
  ((ushort4*)dst)[i] = o;
}

// ---------------- bf16 MFMA GEMM: C[M,N] = A[M,K] * W[N,K]^T ----------------
__global__ __launch_bounds__(256) void gemm_bf16(const unsigned short* __restrict__ A,
                                                 const unsigned short* __restrict__ W,
                                                 float* __restrict__ C,
                                                 int M, int N, int K) {
  __shared__ __align__(16) unsigned short As[64][32];
  __shared__ __align__(16) unsigned short Bs[64][32];
  const int m0 = blockIdx.x * 64, n0 = blockIdx.y * 64;
  const int t = threadIdx.x;
  const int wave = t >> 6, lane = t & 63;
  const int fr = lane & 15, quad = lane >> 4, k0 = quad * 8;
  const int srow = t >> 2, scol = (t & 3) * 8;

  f32x4 acc[4];
#pragma unroll
  for (int i = 0; i < 4; i++) acc[i] = (f32x4){0.f, 0.f, 0.f, 0.f};

  const unsigned short* Arow = A + (size_t)(m0 + srow) * K + scol;
  const unsigned short* Wrow = W + (size_t)(n0 + srow) * K + scol;

  for (int kk = 0; kk < K; kk += 32) {
    *(uint4*)&As[srow][scol] = *(const uint4*)(Arow + kk);
    *(uint4*)&Bs[srow][scol] = *(const uint4*)(Wrow + kk);
    __syncthreads();
    v8bf a = *(const v8bf*)&As[wave * 16 + fr][k0];
#pragma unroll
    for (int nt = 0; nt < 4; nt++) {
      v8bf b = *(const v8bf*)&Bs[nt * 16 + fr][k0];
      acc[nt] = __builtin_amdgcn_mfma_f32_16x16x32_bf16(a, b, acc[nt], 0, 0, 0);
    }
    __syncthreads();
  }

  const int orow = m0 + wave * 16 + quad * 4;
#pragma unroll
  for (int nt = 0; nt < 4; nt++) {
    int oc = n0 + nt * 16 + fr;
#pragma unroll
    for (int rr = 0; rr < 4; rr++)
      C[(size_t)(orow + rr) * N + oc] = acc[nt][rr];
  }
}

// ---------------- RoPE + sample-var norm; fp32 [bt][C] -> bf16 [b][h][t][d] ----
__global__ __launch_bounds__(256) void rope_norm_kernel(const float* __restrict__ src,
                                                        unsigned short* __restrict__ dst,
                                                        const float* __restrict__ cosb,
                                                        const float* __restrict__ sinb) {
  int idx = blockIdx.x * 4 + (threadIdx.x >> 6);   // (b*T + t)*H + h
  int lane = threadIdx.x & 63;
  int h = idx % HH;
  int bt = idx / HH;
  int tpos = bt & (TT - 1);
  int b = bt >> 11;
  size_t base = (size_t)bt * CC + h * DD;

  float x1 = src[base + lane];
  float x2 = src[base + HALF + lane];
  float c = cosb[tpos * HALF + lane];
  float s = sinb[tpos * HALF + lane];
  float o1 = x1 * c + x2 * s;
  float o2 = x2 * c - x1 * s;

  float sum = o1 + o2;
#pragma unroll
  for (int off = 32; off; off >>= 1) sum += __shfl_xor(sum, off);
  float mean = sum * (1.f / 128.f);
  float d1 = o1 - mean, d2 = o2 - mean;
  float vs = d1 * d1 + d2 * d2;
#pragma unroll
  for (int off = 32; off; off >>= 1) vs += __shfl_xor(vs, off);
  float inv = 1.f / (sqrtf(vs * (1.f / 127.f)) + 1e-6f);

  size_t obase = (((size_t)b * HH + h) * TT + tpos) * DD;
  dst[obase + lane] = f2b(d1 * inv);
  dst[obase + HALF + lane] = f2b(d2 * inv);
}

// ---------------- V transpose: fp32 [bt][C] -> bf16 [b][h][d][t] ----------------
__global__ __launch_bounds__(256) void transpose_v(const float* __restrict__ v,
                                                   unsigned short* __restrict__ vt) {
  __shared__ unsigned short tile[64][68];   // [t][d], pad 68 (136B rows, 8B-aligned)
  int t0 = blockIdx.x * 64;
  int d0 = blockIdx.y * 64;
  int bh = blockIdx.z;
  int b = bh / HH, h = bh % HH;
  int tid = threadIdx.x;
  int rr = tid >> 4, cc = (tid & 15) * 4;
#pragma unroll
  for (int it = 0; it < 4; it++) {
    int row = rr + it * 16;   // t index
    float4 f = *(const float4*)&v[((size_t)b * TT + t0 + row) * CC + h * DD + d0 + cc];
    ushort4 u = { f2b(f.x), f2b(f.y), f2b(f.z), f2b(f.w) };
    *(ushort4*)&tile[row][cc] = u;
  }
  __syncthreads();
#pragma unroll
  for (int it = 0; it < 4; it++) {
    int drow = rr + it * 16;  // d index within tile
    ushort4 u = { tile[cc + 0][drow], tile[cc + 1][drow],
                  tile[cc + 2][drow], tile[cc + 3][drow] };
    *(ushort4*)&vt[(((size_t)bh) * DD + d0 + drow) * TT + t0 + cc] = u;
  }
}

// ---------------- MFMA flash attention (causal, bf16 in / fp32 acc) ----------------
// grid = (T/64, B*H). 4 waves; wave owns 16 Q-rows. K-tile = 32.
// S^T trick: compute D = K_frag * Q_frag so C-layout gives col=fr=Q-row ->
// per-lane softmax stats for ONE row; reductions are shfl_xor(16),(32).
// P round-trips LDS (C-layout write as ushort4, A-layout 16B read).
__global__ __launch_bounds__(256) void attn_mfma(const unsigned short* __restrict__ qtb,
                                                 const unsigned short* __restrict__ ktb,
                                                 const unsigned short* __restrict__ vtb,
                                                 unsigned short* __restrict__ yb) {
  __shared__ __align__(16) unsigned short Ks[32][136];    // K-tile [s][d], pad 136
  __shared__ __align__(16) unsigned short Vts[128][40];   // V^T tile [d][s], pad 40
  __shared__ __align__(16) unsigned short Ps[4][16][40];  // per-wave P [m][s], pad 40

  const int qt = (int)gridDim.x - 1 - (int)blockIdx.x;    // heavy tiles first
  const int bh = blockIdx.y;
  const int b = bh / HH, h = bh % HH;
  const int tid = threadIdx.x;
  const int wave = tid >> 6, lane = tid & 63;
  const int fr = lane & 15, quad = lane >> 4;

  const size_t head_base = (size_t)bh * TT * DD;
  const int m0 = qt * 64 + wave * 16;

  // Q fragments (A/B layout): lane holds Q[m0+fr][quad*8 + 32*kb + j]
  v8bf qf[4];
#pragma unroll
  for (int kb = 0; kb < 4; kb++)
    qf[kb] = *(const v8bf*)(qtb + head_base + (size_t)(m0 + fr) * DD + kb * 32 + quad * 8);

  f32x4 oacc[8];
#pragma unroll
  for (int i = 0; i < 8; i++) oacc[i] = (f32x4){0.f, 0.f, 0.f, 0.f};
  float m_i = -1e30f, l_i = 0.f;
  const int qrow = m0 + fr;    // the Q row this lane tracks softmax stats for

  const int ntiles = (qt + 1) * 2;
  for (int jt = 0; jt < ntiles; jt++) {
    const int j0 = jt * 32;
    __syncthreads();
    {
      // stage K tile: 8 KB contiguous; 512 chunks of 16B
      int c = tid;
#pragma unroll
      for (int it = 0; it < 2; it++, c += 256) {
        int s = c >> 4, col = (c & 15) * 8;
        *(uint4*)&Ks[s][col] = *(const uint4*)(ktb + head_base + (size_t)(j0 + s) * DD + col);
      }
      // stage V^T tile: 128 d-rows x 32 s, 64B per global row
      c = tid;
#pragma unroll
      for (int it = 0; it < 2; it++, c += 256) {
        int d = c >> 2, off = (c & 3) * 8;
        *(uint4*)&Vts[d][off] = *(const uint4*)(vtb + head_base + (size_t)d * TT + j0 + off);
      }
    }
    __syncthreads();

    if (j0 > m0 + 15) continue;   // wave fully masked (barriers already passed)

    // S^T = K_tile · Q^T : D[n=K-col (row)][m=Q-row (col=fr)]
    f32x4 st0 = {0.f, 0.f, 0.f, 0.f}, st1 = {0.f, 0.f, 0.f, 0.f};
#pragma unroll
    for (int kb = 0; kb < 4; kb++) {
      v8bf a0 = *(const v8bf*)&Ks[fr][kb * 32 + quad * 8];
      v8bf a1 = *(const v8bf*)&Ks[fr + 16][kb * 32 + quad * 8];
      st0 = __builtin_amdgcn_mfma_f32_16x16x32_bf16(a0, qf[kb], st0, 0, 0, 0);
      st1 = __builtin_amdgcn_mfma_f32_16x16x32_bf16(a1, qf[kb], st1, 0, 0, 0);
    }

    // mask + scale; lane's K-cols: j0 + {0,16} + quad*4 + r, Q-row = qrow
    float p[8];
    const int ncol0 = j0 + quad * 4;
    float mx = -1e30f;
#pragma unroll
    for (int r = 0; r < 4; r++) {
      float a = (ncol0 + r <= qrow) ? st0[r] * SCALE : -1e30f;
      float c2 = (ncol0 + 16 + r <= qrow) ? st1[r] * SCALE : -1e30f;
      p[r] = a; p[4 + r] = c2;
      mx = fmaxf(mx, fmaxf(a, c2));
    }
    mx = fmaxf(mx, __shfl_xor(mx, 16));
    mx = fmaxf(mx, __shfl_xor(mx, 32));
    float m_new = fmaxf(m_i, mx);
    float alpha = __expf(m_i - m_new);
    m_i = m_new;
    float ps = 0.f;
#pragma unroll
    for (int i = 0; i < 8; i++) { p[i] = __expf(p[i] - m_new); ps += p[i]; }
    ps += __shfl_xor(ps, 16);
    ps += __shfl_xor(ps, 32);
    l_i = alpha * l_i + ps;

    // write P (bf16): row m=fr, cols nt*16 + quad*4 + r  (two packed ushort4)
    ushort4 w0 = { f2b(p[0]), f2b(p[1]), f2b(p[2]), f2b(p[3]) };
    ushort4 w1 = { f2b(p[4]), f2b(p[5]), f2b(p[6]), f2b(p[7]) };
    *(ushort4*)&Ps[wave][fr][quad * 4] = w0;
    *(ushort4*)&Ps[wave][fr][16 + quad * 4] = w1;

    // rescale O: alpha is per-row(fr); O rows are quad*4+r -> broadcast
    float al[4];
#pragma unroll
    for (int r = 0; r < 4; r++) al[r] = __shfl(alpha, quad * 4 + r, 16);
#pragma unroll
    for (int i = 0; i < 8; i++) {
      oacc[i][0] *= al[0]; oacc[i][1] *= al[1];
      oacc[i][2] *= al[2]; oacc[i][3] *= al[3];
    }

    // PV: O[m][d] += P[m][s] V[s][d];  A = P (rows=fr), B = V^T (rows=d)
    v8bf pa = *(const v8bf*)&Ps[wave][fr][quad * 8];
#pragma unroll
    for (int nt2 = 0; nt2 < 8; nt2++) {
      v8bf vb = *(const v8bf*)&Vts[nt2 * 16 + fr][quad * 8];
      oacc[nt2] = __builtin_amdgcn_mfma_f32_16x16x32_bf16(pa, vb, oacc[nt2], 0, 0, 0);
    }
  }

  // epilogue: O rows m0+quad*4+r, col d = nt2*16+fr; scale by 1/l(row)
  float linv[4];
#pragma unroll
  for (int r = 0; r < 4; r++) {
    float lr = __shfl(l_i, quad * 4 + r, 16);
    linv[r] = 1.f / lr;
  }
  const size_t out_row_base = ((size_t)b * TT + (size_t)(m0 + quad * 4)) * CC + h * DD;
#pragma unroll
  for (int nt2 = 0; nt2 < 8; nt2++) {
#pragma unroll
    for (int r = 0; r < 4; r++)
      yb[out_row_base + (size_t)r * CC + nt2 * 16 + fr] = f2b(oacc[nt2][r] * linv[r]);
  }
}

// ---------------- launch ----------------
extern "C" void kernel_launch(void* const* d_in, const int* in_sizes, int n_in,
                              void* d_out, int out_size, void* d_ws, size_t ws_size,
                              hipStream_t stream) {
  const float* x     = (const float*)d_in[0];
  const float* cosb  = (const float*)d_in[1];
  const float* sinb  = (const float*)d_in[2];
  const float* wq    = (const float*)d_in[3];
  const float* wk    = (const float*)d_in[4];
  const float* wv    = (const float*)d_in[5];
  const float* wproj = (const float*)d_in[6];
  float* out = (float*)d_out;

  // workspace layout (117,964,800 bytes total):
  //   0        : q fp32 (25165824)  -> later reused as yb bf16 (attn output)
  //   25165824 : k fp32 (25165824)
  //   50331648 : v fp32 (25165824)
  //   75497472 : k_t bf16 [b][h][t][d] (12582912)
  //   88080384 : v_t bf16 [b][h][d][t] (12582912)
  //  100663296 : xb bf16 (12582912)  -> reused as q_t after QKV GEMMs
  //  113246208 : wqb/wkb/wvb/wpb bf16 (4x1179648)
  char* w = (char*)d_ws;
  float* q  = (float*)(w);
  float* kk = (float*)(w + 25165824);
  float* v  = (float*)(w + 50331648);
  unsigned short* k_t = (unsigned short*)(w + 75497472);
  unsigned short* v_t = (unsigned short*)(w + 88080384);
  unsigned short* xb  = (unsigned short*)(w + 100663296);
  unsigned short* q_t = xb;                               // alias: xb dead after GEMMs
  unsigned short* yb  = (unsigned short*)(w);             // alias: q fp32 dead after rope
  unsigned short* wqb = (unsigned short*)(w + 113246208);
  unsigned short* wkb = (unsigned short*)(w + 114425856);
  unsigned short* wvb = (unsigned short*)(w + 115605504);
  unsigned short* wpb = (unsigned short*)(w + 116785152);

  const int nx4 = BT * CC / 4;
  const int nw4 = CC * CC / 4;

  cvt_f2b_kernel<<<(nx4 + 255) / 256, 256, 0, stream>>>(x, xb, nx4);
  cvt_f2b_kernel<<<(nw4 + 255) / 256, 256, 0, stream>>>(wq, wqb, nw4);
  cvt_f2b_kernel<<<(nw4 + 255) / 256, 256, 0, stream>>>(wk, wkb, nw4);
  cvt_f2b_kernel<<<(nw4 + 255) / 256, 256, 0, stream>>>(wv, wvb, nw4);
  cvt_f2b_kernel<<<(nw4 + 255) / 256, 256, 0, stream>>>(wproj, wpb, nw4);

  dim3 ggrid(BT / 64, CC / 64);
  gemm_bf16<<<ggrid, 256, 0, stream>>>(xb, wqb, q, BT, CC, CC);
  gemm_bf16<<<ggrid, 256, 0, stream>>>(xb, wkb, kk, BT, CC, CC);
  gemm_bf16<<<ggrid, 256, 0, stream>>>(xb, wvb, v, BT, CC, CC);

  int nvec = BT * HH;  // 49152 (b,t,h) vectors
  rope_norm_kernel<<<nvec / 4, 256, 0, stream>>>(q, q_t, cosb, sinb);   // writes into xb region
  rope_norm_kernel<<<nvec / 4, 256, 0, stream>>>(kk, k_t, cosb, sinb);
  transpose_v<<<dim3(TT / 64, DD / 64, BB * HH), 256, 0, stream>>>(v, v_t);

  attn_mfma<<<dim3(TT / 64, BB * HH), 256, 0, stream>>>(q_t, k_t, v_t, yb);

  gemm_bf16<<<ggrid, 256, 0, stream>>>(yb, wpb, out, BT, CC, CC);
}

// Round 3
// 293.082 us; speedup vs baseline: 5.5276x; 1.2336x over previous
//
#include <hip/hip_runtime.h>

// Problem constants (CausalSelfAttention: B=4 T=2048 C=768 H=KVH=6 D=128)
#define BB 4
#define TT 2048
#define CC 768
#define HH 6
#define DD 128
#define BT (BB * TT)          // 8192 rows
#define HALF 64
// combined scale for exp2-domain softmax: exp(s/sqrt(128)) = exp2(s * QKSCALE)
#define QKSCALE 0.12753785627919282f   // (1/sqrt(128)) * log2(e)

typedef __bf16 v8bf __attribute__((ext_vector_type(8)));
typedef float f32x4 __attribute__((ext_vector_type(4)));

// ---------------- fp32 -> bf16 (RNE) ----------------
__device__ __forceinline__ unsigned short f2b(float f) {
  union { float f; unsigned u; } v; v.f = f;
  unsigned r = v.u + 0x7FFFu + ((v.u >> 16) & 1u);
  return (unsigned short)(r >> 16);
}

// async global->LDS, 16B per lane; lds base must be wave-uniform, deposit at base + lane*16
__device__ __forceinline__ void load_lds16(const void* g, void* l) {
  __builtin_amdgcn_global_load_lds(
      (const __attribute__((address_space(1))) unsigned int*)g,
      (__attribute__((address_space(3))) unsigned int*)(unsigned int)(unsigned long long)(l),
      16, 0, 0);
}

__global__ __launch_bounds__(256) void cvt_f2b_kernel(const float* __restrict__ src,
                                                      unsigned short* __restrict__ dst,
                                                      int n4) {
  int i = blockIdx.x * 256 + threadIdx.x;
  if (i >= n4) return;
  float4 f = ((const float4*)src)[i];
  ushort4 o;
  o.x = f2b(f.x); o.y = f2b(f.y); o.z = f2b(f.z); o.w = f2b(f.w);
  ((ushort4*)dst)[i] = o;
}

// ---------------- bf16 MFMA GEMM: C[M,N] = A[M,K] * W[N,K]^T ----------------
// m97-style: 128x128 tile, BK=32, 256 thr = 4 waves (wave quadrant 64x64, 4x4 frags).
// Staging via global_load_lds(16B), double-buffered LDS, XOR-swizzled slot layout:
//   slot(r,g) = 4r + (g ^ ((r>>1)&3)), g in 0..3 (16B k-groups of a 64B row)
// -> frag read bank-group = 4(fr&1) + (quad ^ ((fr>>1)&3)): uniform, 2-way = free.
__global__ __launch_bounds__(256) void gemm_bf16(const unsigned short* __restrict__ A,
                                                 const unsigned short* __restrict__ W,
                                                 float* __restrict__ C,
                                                 int M, int N, int K) {
  __shared__ __align__(16) unsigned short As[2][512 * 8];   // 128x32 bf16, swizzled
  __shared__ __align__(16) unsigned short Bs[2][512 * 8];
  const int m0 = blockIdx.x * 128, n0 = blockIdx.y * 128;
  const int tid = threadIdx.x;
  const int wave = tid >> 6, lane = tid & 63;
  const int fr = lane & 15, quad = lane >> 4;
  const int wm = (wave & 1) * 64, wn = (wave >> 1) * 64;

  f32x4 acc[4][4];
#pragma unroll
  for (int i = 0; i < 4; i++)
#pragma unroll
    for (int j = 0; j < 4; j++) acc[i][j] = (f32x4){0.f, 0.f, 0.f, 0.f};

  const int nsteps = K / 32;

  auto stage = [&](int kk, int buf) {
#pragma unroll
    for (int it = 0; it < 2; it++) {
      int base_slot = wave * 128 + it * 64;
      int sigma = base_slot + lane;
      int r = sigma >> 2, g = (sigma & 3) ^ ((r >> 1) & 3);
      load_lds16(A + (size_t)(m0 + r) * K + kk + g * 8, &As[buf][base_slot * 8]);
      load_lds16(W + (size_t)(n0 + r) * K + kk + g * 8, &Bs[buf][base_slot * 8]);
    }
  };

  stage(0, 0);
  __syncthreads();
  for (int step = 0; step < nsteps; step++) {
    int buf = step & 1;
    if (step + 1 < nsteps) stage((step + 1) * 32, buf ^ 1);
    v8bf af[4], bfr[4];
#pragma unroll
    for (int i = 0; i < 4; i++) {
      int ra = wm + i * 16 + fr;
      af[i] = *(const v8bf*)&As[buf][(4 * ra + (quad ^ ((ra >> 1) & 3))) * 8];
      int rb = wn + i * 16 + fr;
      bfr[i] = *(const v8bf*)&Bs[buf][(4 * rb + (quad ^ ((rb >> 1) & 3))) * 8];
    }
#pragma unroll
    for (int i = 0; i < 4; i++)
#pragma unroll
      for (int j = 0; j < 4; j++)
        acc[i][j] = __builtin_amdgcn_mfma_f32_16x16x32_bf16(af[i], bfr[j], acc[i][j], 0, 0, 0);
    __syncthreads();
  }

  const int orow = m0 + wm + quad * 4;
#pragma unroll
  for (int i = 0; i < 4; i++)
#pragma unroll
    for (int j = 0; j < 4; j++) {
      int oc = n0 + wn + j * 16 + fr;
#pragma unroll
      for (int r = 0; r < 4; r++)
        C[(size_t)(orow + i * 16 + r) * N + oc] = acc[i][j][r];
    }
}

// ---------------- RoPE + sample-var norm; fp32 [bt][C] -> bf16 [b][h][t][d] ----
__global__ __launch_bounds__(256) void rope_norm_kernel(const float* __restrict__ src,
                                                        unsigned short* __restrict__ dst,
                                                        const float* __restrict__ cosb,
                                                        const float* __restrict__ sinb) {
  int idx = blockIdx.x * 4 + (threadIdx.x >> 6);   // (b*T + t)*H + h
  int lane = threadIdx.x & 63;
  int h = idx % HH;
  int bt = idx / HH;
  int tpos = bt & (TT - 1);
  int b = bt >> 11;
  size_t base = (size_t)bt * CC + h * DD;

  float x1 = src[base + lane];
  float x2 = src[base + HALF + lane];
  float c = cosb[tpos * HALF + lane];
  float s = sinb[tpos * HALF + lane];
  float o1 = x1 * c + x2 * s;
  float o2 = x2 * c - x1 * s;

  float sum = o1 + o2;
#pragma unroll
  for (int off = 32; off; off >>= 1) sum += __shfl_xor(sum, off);
  float mean = sum * (1.f / 128.f);
  float d1 = o1 - mean, d2 = o2 - mean;
  float vs = d1 * d1 + d2 * d2;
#pragma unroll
  for (int off = 32; off; off >>= 1) vs += __shfl_xor(vs, off);
  float inv = 1.f / (sqrtf(vs * (1.f / 127.f)) + 1e-6f);

  size_t obase = (((size_t)b * HH + h) * TT + tpos) * DD;
  dst[obase + lane] = f2b(d1 * inv);
  dst[obase + HALF + lane] = f2b(d2 * inv);
}

// ---------------- V transpose: fp32 [bt][C] -> bf16 [b][h][d][t] ----------------
__global__ __launch_bounds__(256) void transpose_v(const float* __restrict__ v,
                                                   unsigned short* __restrict__ vt) {
  __shared__ unsigned short tile[64][68];
  int t0 = blockIdx.x * 64;
  int d0 = blockIdx.y * 64;
  int bh = blockIdx.z;
  int b = bh / HH, h = bh % HH;
  int tid = threadIdx.x;
  int rr = tid >> 4, cc = (tid & 15) * 4;
#pragma unroll
  for (int it = 0; it < 4; it++) {
    int row = rr + it * 16;
    float4 f = *(const float4*)&v[((size_t)b * TT + t0 + row) * CC + h * DD + d0 + cc];
    ushort4 u = { f2b(f.x), f2b(f.y), f2b(f.z), f2b(f.w) };
    *(ushort4*)&tile[row][cc] = u;
  }
  __syncthreads();
#pragma unroll
  for (int it = 0; it < 4; it++) {
    int drow = rr + it * 16;
    ushort4 u = { tile[cc + 0][drow], tile[cc + 1][drow],
                  tile[cc + 2][drow], tile[cc + 3][drow] };
    *(ushort4*)&vt[(((size_t)bh) * DD + d0 + drow) * TT + t0 + cc] = u;
  }
}

// ---------------- MFMA flash attention v3 (causal, no-max softmax) ----------------
// 768 blocks x 128 thr (2 waves). Block = 64 Q rows, wave = 32 Q rows (2 fr-sets).
// qt = 31 - L/24 breaks the qt<->CU aliasing (R2 pathology: 256 = 0 mod 32).
// No-max softmax is safe: |q|=|k|=sqrt(127) after _norm -> |s*scale| <= 11.23.
// K/V staged via global_load_lds into double-buffered swizzled LDS:
//   K slot(s,g) = 16s + (g ^ (s&7)),  g in 0..15  (row = 16 x 16B groups)
//   V slot(d,g) =  4d + (g ^ ((d>>1)&3)), g in 0..3
__global__ __launch_bounds__(128) void attn_mfma(const unsigned short* __restrict__ qtb,
                                                 const unsigned short* __restrict__ ktb,
                                                 const unsigned short* __restrict__ vtb,
                                                 unsigned short* __restrict__ yb) {
  __shared__ __align__(16) unsigned short Ks[2][512 * 8];   // 32 x 128 bf16
  __shared__ __align__(16) unsigned short Vts[2][512 * 8];  // 128 x 32 bf16 (V^T)
  __shared__ __align__(16) unsigned short Ps[2][32][40];    // per-wave P, pad 40

  const int L = blockIdx.x;
  const int bh = L % (BB * HH);
  const int qt = (TT / 64 - 1) - L / (BB * HH);   // heavy-first, de-aliased
  const int b = bh / HH, h = bh % HH;
  const int tid = threadIdx.x;
  const int wave = tid >> 6, lane = tid & 63;
  const int fr = lane & 15, quad = lane >> 4;

  const size_t head_base = (size_t)bh * TT * DD;
  const int m0 = qt * 64 + wave * 32;             // wave's first Q row

  // Q fragments: 2 sets of 16 rows, A/B-layout direct from global
  v8bf qf[2][4];
#pragma unroll
  for (int qs = 0; qs < 2; qs++)
#pragma unroll
    for (int kb = 0; kb < 4; kb++)
      qf[qs][kb] = *(const v8bf*)(qtb + head_base +
                                  (size_t)(m0 + qs * 16 + fr) * DD + kb * 32 + quad * 8);

  f32x4 oacc[2][8];
#pragma unroll
  for (int qs = 0; qs < 2; qs++)
#pragma unroll
    for (int i = 0; i < 8; i++) oacc[qs][i] = (f32x4){0.f, 0.f, 0.f, 0.f};
  float lsum[2] = {0.f, 0.f};

  const int ntiles = 2 * qt + 2;

  auto stage = [&](int jt, int buf) {
    const unsigned short* kbase = ktb + head_base + (size_t)(jt * 32) * DD;
    const unsigned short* vbase = vtb + head_base + jt * 32;
#pragma unroll
    for (int it = 0; it < 4; it++) {
      int base_slot = wave * 256 + it * 64;
      int sigma = base_slot + lane;
      int s = sigma >> 4, gk = (sigma & 15) ^ (s & 7);
      load_lds16(kbase + (size_t)s * DD + gk * 8, &Ks[buf][base_slot * 8]);
      int d = sigma >> 2, gv = (sigma & 3) ^ ((d >> 1) & 3);
      load_lds16(vbase + (size_t)d * TT + gv * 8, &Vts[buf][base_slot * 8]);
    }
  };

  stage(0, 0);
  __syncthreads();

  for (int jt = 0; jt < ntiles; jt++) {
    const int buf = jt & 1;
    if (jt + 1 < ntiles) stage(jt + 1, buf ^ 1);

    if (jt * 32 <= m0 + 31) {        // wave not fully masked (uniform branch)
      const int j0 = jt * 32;
      // S^T = K_tile . Q^T  (D[m=K-col][n=Q-row]); K-frags shared across both Q-sets
      f32x4 st[2][2];
#pragma unroll
      for (int qs = 0; qs < 2; qs++) { st[qs][0] = (f32x4){0,0,0,0}; st[qs][1] = (f32x4){0,0,0,0}; }
#pragma unroll
      for (int kb = 0; kb < 4; kb++) {
        int g = 4 * kb + quad;
        v8bf a0 = *(const v8bf*)&Ks[buf][(16 * fr + (g ^ (fr & 7))) * 8];
        v8bf a1 = *(const v8bf*)&Ks[buf][(16 * (fr + 16) + (g ^ (fr & 7))) * 8];
        st[0][0] = __builtin_amdgcn_mfma_f32_16x16x32_bf16(a0, qf[0][kb], st[0][0], 0, 0, 0);
        st[0][1] = __builtin_amdgcn_mfma_f32_16x16x32_bf16(a1, qf[0][kb], st[0][1], 0, 0, 0);
        st[1][0] = __builtin_amdgcn_mfma_f32_16x16x32_bf16(a0, qf[1][kb], st[1][0], 0, 0, 0);
        st[1][1] = __builtin_amdgcn_mfma_f32_16x16x32_bf16(a1, qf[1][kb], st[1][1], 0, 0, 0);
      }

      // softmax (no max-tracking): p = exp2(s * QKSCALE); masked -> 0
#pragma unroll
      for (int qs = 0; qs < 2; qs++) {
        const int qrow = m0 + qs * 16 + fr;
        float p[8]; float ls = 0.f;
#pragma unroll
        for (int r = 0; r < 4; r++) {
          int c0 = j0 + quad * 4 + r;
          p[r]     = (c0      <= qrow) ? exp2f(st[qs][0][r] * QKSCALE) : 0.f;
          p[4 + r] = (c0 + 16 <= qrow) ? exp2f(st[qs][1][r] * QKSCALE) : 0.f;
          ls += p[r] + p[4 + r];
        }
        lsum[qs] += ls;
        ushort4 w0 = { f2b(p[0]), f2b(p[1]), f2b(p[2]), f2b(p[3]) };
        ushort4 w1 = { f2b(p[4]), f2b(p[5]), f2b(p[6]), f2b(p[7]) };
        *(ushort4*)&Ps[wave][qs * 16 + fr][quad * 4] = w0;
        *(ushort4*)&Ps[wave][qs * 16 + fr][16 + quad * 4] = w1;
      }

      // PV: O[m][d] += P[m][s] V^T[d][s];  V-frags shared across both Q-sets
      v8bf pa0 = *(const v8bf*)&Ps[wave][fr][quad * 8];
      v8bf pa1 = *(const v8bf*)&Ps[wave][16 + fr][quad * 8];
#pragma unroll
      for (int nt2 = 0; nt2 < 8; nt2++) {
        int d = nt2 * 16 + fr;
        v8bf vb = *(const v8bf*)&Vts[buf][(4 * d + (quad ^ ((d >> 1) & 3))) * 8];
        oacc[0][nt2] = __builtin_amdgcn_mfma_f32_16x16x32_bf16(pa0, vb, oacc[0][nt2], 0, 0, 0);
        oacc[1][nt2] = __builtin_amdgcn_mfma_f32_16x16x32_bf16(pa1, vb, oacc[1][nt2], 0, 0, 0);
      }
    }
    __syncthreads();
  }

  // epilogue: rows m0 + qs*16 + quad*4 + r, col d = nt2*16 + fr
#pragma unroll
  for (int qs = 0; qs < 2; qs++) {
    float l = lsum[qs];
    l += __shfl_xor(l, 16);
    l += __shfl_xor(l, 32);
    float linv[4];
#pragma unroll
    for (int r = 0; r < 4; r++) linv[r] = 1.f / __shfl(l, quad * 4 + r, 16);
    const size_t out_base = ((size_t)b * TT + (size_t)(m0 + qs * 16 + quad * 4)) * CC + h * DD;
#pragma unroll
    for (int nt2 = 0; nt2 < 8; nt2++)
#pragma unroll
      for (int r = 0; r < 4; r++)
        yb[out_base + (size_t)r * CC + nt2 * 16 + fr] = f2b(oacc[qs][nt2][r] * linv[r]);
  }
}

// ---------------- launch ----------------
extern "C" void kernel_launch(void* const* d_in, const int* in_sizes, int n_in,
                              void* d_out, int out_size, void* d_ws, size_t ws_size,
                              hipStream_t stream) {
  const float* x     = (const float*)d_in[0];
  const float* cosb  = (const float*)d_in[1];
  const float* sinb  = (const float*)d_in[2];
  const float* wq    = (const float*)d_in[3];
  const float* wk    = (const float*)d_in[4];
  const float* wv    = (const float*)d_in[5];
  const float* wproj = (const float*)d_in[6];
  float* out = (float*)d_out;

  char* w = (char*)d_ws;
  float* q  = (float*)(w);
  float* kk = (float*)(w + 25165824);
  float* v  = (float*)(w + 50331648);
  unsigned short* k_t = (unsigned short*)(w + 75497472);
  unsigned short* v_t = (unsigned short*)(w + 88080384);
  unsigned short* xb  = (unsigned short*)(w + 100663296);
  unsigned short* q_t = xb;                               // alias: xb dead after GEMMs
  unsigned short* yb  = (unsigned short*)(w);             // alias: q fp32 dead after rope
  unsigned short* wqb = (unsigned short*)(w + 113246208);
  unsigned short* wkb = (unsigned short*)(w + 114425856);
  unsigned short* wvb = (unsigned short*)(w + 115605504);
  unsigned short* wpb = (unsigned short*)(w + 116785152);

  const int nx4 = BT * CC / 4;
  const int nw4 = CC * CC / 4;

  cvt_f2b_kernel<<<(nx4 + 255) / 256, 256, 0, stream>>>(x, xb, nx4);
  cvt_f2b_kernel<<<(nw4 + 255) / 256, 256, 0, stream>>>(wq, wqb, nw4);
  cvt_f2b_kernel<<<(nw4 + 255) / 256, 256, 0, stream>>>(wk, wkb, nw4);
  cvt_f2b_kernel<<<(nw4 + 255) / 256, 256, 0, stream>>>(wv, wvb, nw4);
  cvt_f2b_kernel<<<(nw4 + 255) / 256, 256, 0, stream>>>(wproj, wpb, nw4);

  dim3 ggrid(BT / 128, CC / 128);   // 64 x 6
  gemm_bf16<<<ggrid, 256, 0, stream>>>(xb, wqb, q, BT, CC, CC);
  gemm_bf16<<<ggrid, 256, 0, stream>>>(xb, wkb, kk, BT, CC, CC);
  gemm_bf16<<<ggrid, 256, 0, stream>>>(xb, wvb, v, BT, CC, CC);

  int nvec = BT * HH;  // 49152 (b,t,h) vectors
  rope_norm_kernel<<<nvec / 4, 256, 0, stream>>>(q, q_t, cosb, sinb);
  rope_norm_kernel<<<nvec / 4, 256, 0, stream>>>(kk, k_t, cosb, sinb);
  transpose_v<<<dim3(TT / 64, DD / 64, BB * HH), 256, 0, stream>>>(v, v_t);

  attn_mfma<<<(TT / 64) * BB * HH, 128, 0, stream>>>(q_t, k_t, v_t, yb);

  gemm_bf16<<<ggrid, 256, 0, stream>>>(yb, wpb, out, BT, CC, CC);
}

// Round 4
// 245.415 us; speedup vs baseline: 6.6012x; 1.1942x over previous
//
#include <hip/hip_runtime.h>

// Problem constants (CausalSelfAttention: B=4 T=2048 C=768 H=KVH=6 D=128)
#define BB 4
#define TT 2048
#define CC 768
#define HH 6
#define DD 128
#define BT (BB * TT)          // 8192 rows
#define HALF 64
// combined scale for exp2-domain softmax: exp(s/sqrt(128)) = exp2(s * QKSCALE)
#define QKSCALE 0.12753785627919282f   // (1/sqrt(128)) * log2(e)

typedef __bf16 v8bf __attribute__((ext_vector_type(8)));
typedef float f32x4 __attribute__((ext_vector_type(4)));

// ---------------- fp32 -> bf16 (RNE) ----------------
__device__ __forceinline__ unsigned short f2b(float f) {
  union { float f; unsigned u; } v; v.f = f;
  unsigned r = v.u + 0x7FFFu + ((v.u >> 16) & 1u);
  return (unsigned short)(r >> 16);
}

// async global->LDS, 16B per lane; lds base wave-uniform, deposit at base + lane*16
__device__ __forceinline__ void load_lds16(const void* g, void* l) {
  __builtin_amdgcn_global_load_lds(
      (const __attribute__((address_space(1))) unsigned int*)g,
      (__attribute__((address_space(3))) unsigned int*)(unsigned int)(unsigned long long)(l),
      16, 0, 0);
}

__global__ __launch_bounds__(256) void cvt_f2b_kernel(const float* __restrict__ src,
                                                      unsigned short* __restrict__ dst,
                                                      int n4) {
  int i = blockIdx.x * 256 + threadIdx.x;
  if (i >= n4) return;
  float4 f = ((const float4*)src)[i];
  ushort4 o;
  o.x = f2b(f.x); o.y = f2b(f.y); o.z = f2b(f.z); o.w = f2b(f.w);
  ((ushort4*)dst)[i] = o;
}

// all 4 weights (768x768 each) -> contiguous bf16 wb[4][768*768]
__global__ __launch_bounds__(256) void cvt_w4_kernel(const float* __restrict__ w0,
                                                     const float* __restrict__ w1,
                                                     const float* __restrict__ w2,
                                                     const float* __restrict__ w3,
                                                     unsigned short* __restrict__ dst) {
  int bsel = blockIdx.x / 576;                       // 576 blocks per weight
  int i = (blockIdx.x % 576) * 256 + threadIdx.x;    // float4 index
  const float* src = bsel == 0 ? w0 : bsel == 1 ? w1 : bsel == 2 ? w2 : w3;
  float4 f = ((const float4*)src)[i];
  ushort4 o;
  o.x = f2b(f.x); o.y = f2b(f.y); o.z = f2b(f.z); o.w = f2b(f.w);
  ((ushort4*)(dst + bsel * 589824))[i] = o;
}

// ---------------- fused QKV GEMM (128x128 tile, BK=32, dbuf + swizzled LDS) ----
// grid (64, 18): wsel = by/6 (0=q,1=k,2=v), head h = by%6, n-tile = weight rows
// h*128..h*128+127. wsel 0/1 -> fp32 [bt][768] (rope reads it); wsel 2 -> bf16
// v_t [bh][d][t] directly (kills transpose kernel + v fp32 round-trip).
__global__ __launch_bounds__(256) void gemm_qkv(const unsigned short* __restrict__ A,
                                                const unsigned short* __restrict__ Wall,
                                                float* __restrict__ qout,
                                                float* __restrict__ kout,
                                                unsigned short* __restrict__ vt) {
  __shared__ __align__(16) unsigned short As[2][512 * 8];
  __shared__ __align__(16) unsigned short Bs[2][512 * 8];
  const int m0 = blockIdx.x * 128;
  const int wsel = blockIdx.y / HH, h = blockIdx.y % HH;
  const unsigned short* W = Wall + (size_t)wsel * 589824 + (size_t)h * 128 * CC;
  const int tid = threadIdx.x;
  const int wave = tid >> 6, lane = tid & 63;
  const int fr = lane & 15, quad = lane >> 4;
  const int wm = (wave & 1) * 64, wn = (wave >> 1) * 64;

  f32x4 acc[4][4];
#pragma unroll
  for (int i = 0; i < 4; i++)
#pragma unroll
    for (int j = 0; j < 4; j++) acc[i][j] = (f32x4){0.f, 0.f, 0.f, 0.f};

  auto stage = [&](int kk, int buf) {
#pragma unroll
    for (int it = 0; it < 2; it++) {
      int base_slot = wave * 128 + it * 64;
      int sigma = base_slot + lane;
      int r = sigma >> 2, g = (sigma & 3) ^ ((r >> 1) & 3);
      load_lds16(A + (size_t)(m0 + r) * CC + kk + g * 8, &As[buf][base_slot * 8]);
      load_lds16(W + (size_t)r * CC + kk + g * 8, &Bs[buf][base_slot * 8]);
    }
  };

  stage(0, 0);
  __syncthreads();
  for (int step = 0; step < CC / 32; step++) {
    int buf = step & 1;
    if (step + 1 < CC / 32) stage((step + 1) * 32, buf ^ 1);
    v8bf af[4], bfr[4];
#pragma unroll
    for (int i = 0; i < 4; i++) {
      int ra = wm + i * 16 + fr;
      af[i] = *(const v8bf*)&As[buf][(4 * ra + (quad ^ ((ra >> 1) & 3))) * 8];
      int rb = wn + i * 16 + fr;
      bfr[i] = *(const v8bf*)&Bs[buf][(4 * rb + (quad ^ ((rb >> 1) & 3))) * 8];
    }
#pragma unroll
    for (int i = 0; i < 4; i++)
#pragma unroll
      for (int j = 0; j < 4; j++)
        acc[i][j] = __builtin_amdgcn_mfma_f32_16x16x32_bf16(af[i], bfr[j], acc[i][j], 0, 0, 0);
    __syncthreads();
  }

  if (wsel < 2) {
    float* out = wsel ? kout : qout;
    const int orow = m0 + wm + quad * 4;
#pragma unroll
    for (int i = 0; i < 4; i++)
#pragma unroll
      for (int j = 0; j < 4; j++) {
        int oc = h * 128 + wn + j * 16 + fr;
#pragma unroll
        for (int r = 0; r < 4; r++)
          out[(size_t)(orow + i * 16 + r) * CC + oc] = acc[i][j][r];
      }
  } else {
    // v_t[bh][d][t] bf16: rows rr -> (b, t), cols -> d; 4 consecutive t pack
#pragma unroll
    for (int i = 0; i < 4; i++) {
      int rr0 = m0 + wm + i * 16 + quad * 4;
      int b = rr0 >> 11, t0 = rr0 & 2047;
      int bh = b * HH + h;
#pragma unroll
      for (int j = 0; j < 4; j++) {
        int d = wn + j * 16 + fr;
        ushort4 u = { f2b(acc[i][j][0]), f2b(acc[i][j][1]),
                      f2b(acc[i][j][2]), f2b(acc[i][j][3]) };
        *(ushort4*)&vt[((size_t)bh * DD + d) * TT + t0] = u;
      }
    }
  }
}

// ---------------- wproj GEMM: 64x128 tile (768 blocks -> 3/CU, small tail) ----
__global__ __launch_bounds__(256) void gemm_w64(const unsigned short* __restrict__ A,
                                                const unsigned short* __restrict__ W,
                                                float* __restrict__ C) {
  __shared__ __align__(16) unsigned short As[2][256 * 8];   // 64x32
  __shared__ __align__(16) unsigned short Bs[2][512 * 8];   // 128x32
  const int m0 = blockIdx.x * 64, n0 = blockIdx.y * 128;
  const int tid = threadIdx.x;
  const int wave = tid >> 6, lane = tid & 63;
  const int fr = lane & 15, quad = lane >> 4;
  const int wm = (wave & 1) * 32, wn = (wave >> 1) * 64;

  f32x4 acc[2][4];
#pragma unroll
  for (int i = 0; i < 2; i++)
#pragma unroll
    for (int j = 0; j < 4; j++) acc[i][j] = (f32x4){0.f, 0.f, 0.f, 0.f};

  auto stage = [&](int kk, int buf) {
    {
      int base_slot = wave * 64;
      int sigma = base_slot + lane;
      int r = sigma >> 2, g = (sigma & 3) ^ ((r >> 1) & 3);
      load_lds16(A + (size_t)(m0 + r) * CC + kk + g * 8, &As[buf][base_slot * 8]);
    }
#pragma unroll
    for (int it = 0; it < 2; it++) {
      int base_slot = wave * 128 + it * 64;
      int sigma = base_slot + lane;
      int r = sigma >> 2, g = (sigma & 3) ^ ((r >> 1) & 3);
      load_lds16(W + (size_t)(n0 + r) * CC + kk + g * 8, &Bs[buf][base_slot * 8]);
    }
  };

  stage(0, 0);
  __syncthreads();
  for (int step = 0; step < CC / 32; step++) {
    int buf = step & 1;
    if (step + 1 < CC / 32) stage((step + 1) * 32, buf ^ 1);
    v8bf af[2], bfr[4];
#pragma unroll
    for (int i = 0; i < 2; i++) {
      int ra = wm + i * 16 + fr;
      af[i] = *(const v8bf*)&As[buf][(4 * ra + (quad ^ ((ra >> 1) & 3))) * 8];
    }
#pragma unroll
    for (int j = 0; j < 4; j++) {
      int rb = wn + j * 16 + fr;
      bfr[j] = *(const v8bf*)&Bs[buf][(4 * rb + (quad ^ ((rb >> 1) & 3))) * 8];
    }
#pragma unroll
    for (int i = 0; i < 2; i++)
#pragma unroll
      for (int j = 0; j < 4; j++)
        acc[i][j] = __builtin_amdgcn_mfma_f32_16x16x32_bf16(af[i], bfr[j], acc[i][j], 0, 0, 0);
    __syncthreads();
  }

  const int orow = m0 + wm + quad * 4;
#pragma unroll
  for (int i = 0; i < 2; i++)
#pragma unroll
    for (int j = 0; j < 4; j++) {
      int oc = n0 + wn + j * 16 + fr;
#pragma unroll
      for (int r = 0; r < 4; r++)
        C[(size_t)(orow + i * 16 + r) * CC + oc] = acc[i][j][r];
    }
}

// ---------------- RoPE + sample-var norm; fp32 [bt][C] -> bf16 [b][h][t][d] ----
__global__ __launch_bounds__(256) void rope_norm_kernel(const float* __restrict__ src,
                                                        unsigned short* __restrict__ dst,
                                                        const float* __restrict__ cosb,
                                                        const float* __restrict__ sinb) {
  int idx = blockIdx.x * 4 + (threadIdx.x >> 6);   // (b*T + t)*H + h
  int lane = threadIdx.x & 63;
  int h = idx % HH;
  int bt = idx / HH;
  int tpos = bt & (TT - 1);
  int b = bt >> 11;
  size_t base = (size_t)bt * CC + h * DD;

  float x1 = src[base + lane];
  float x2 = src[base + HALF + lane];
  float c = cosb[tpos * HALF + lane];
  float s = sinb[tpos * HALF + lane];
  float o1 = x1 * c + x2 * s;
  float o2 = x2 * c - x1 * s;

  float sum = o1 + o2;
#pragma unroll
  for (int off = 32; off; off >>= 1) sum += __shfl_xor(sum, off);
  float mean = sum * (1.f / 128.f);
  float d1 = o1 - mean, d2 = o2 - mean;
  float vs = d1 * d1 + d2 * d2;
#pragma unroll
  for (int off = 32; off; off >>= 1) vs += __shfl_xor(vs, off);
  float inv = 1.f / (sqrtf(vs * (1.f / 127.f)) + 1e-6f);

  size_t obase = (((size_t)b * HH + h) * TT + tpos) * DD;
  dst[obase + lane] = f2b(d1 * inv);
  dst[obase + HALF + lane] = f2b(d2 * inv);
}

// ---------------- MFMA flash attention, split-K (causal, no-max softmax) ------
// 1536 blocks x 128 thr: u -> (qt, chunk, bh); each unit does exactly qt+1
// K-tiles (chunk0: [0,qt+1), chunk1: [qt+1,2qt+2)). No-max partials combine by
// ADDITION (O=sum pV, l=sum p) -> fp32 partial (O,l) per chunk, combine kernel
// finishes. 1536 blocks vs 1024 LDS slots -> dynamic dispatch balancing.
__global__ __launch_bounds__(128) void attn_mfma(const unsigned short* __restrict__ qtb,
                                                 const unsigned short* __restrict__ ktb,
                                                 const unsigned short* __restrict__ vtb,
                                                 float* __restrict__ Opart,
                                                 float* __restrict__ lpart) {
  __shared__ __align__(16) unsigned short Ks[2][512 * 8];   // 32 x 128 bf16
  __shared__ __align__(16) unsigned short Vts[2][512 * 8];  // 128 x 32 bf16 (V^T)
  __shared__ __align__(16) unsigned short Ps[2][32][40];    // per-wave P, pad 40

  const int u = blockIdx.x;
  const int qt = (TT / 64 - 1) - u / 48;          // heavy-first
  const int r48 = u % 48;
  const int chunk = r48 / 24;
  const int bh = r48 % 24;
  const int tid = threadIdx.x;
  const int wave = tid >> 6, lane = tid & 63;
  const int fr = lane & 15, quad = lane >> 4;

  const size_t head_base = (size_t)bh * TT * DD;
  const int m0 = qt * 64 + wave * 32;             // wave's first Q row
  const int jt0 = chunk ? (qt + 1) : 0;
  const int niter = qt + 1;

  v8bf qf[2][4];
#pragma unroll
  for (int qs = 0; qs < 2; qs++)
#pragma unroll
    for (int kb = 0; kb < 4; kb++)
      qf[qs][kb] = *(const v8bf*)(qtb + head_base +
                                  (size_t)(m0 + qs * 16 + fr) * DD + kb * 32 + quad * 8);

  f32x4 oacc[2][8];
#pragma unroll
  for (int qs = 0; qs < 2; qs++)
#pragma unroll
    for (int i = 0; i < 8; i++) oacc[qs][i] = (f32x4){0.f, 0.f, 0.f, 0.f};
  float lsum[2] = {0.f, 0.f};

  auto stage = [&](int jt, int buf) {
    const unsigned short* kbase = ktb + head_base + (size_t)(jt * 32) * DD;
    const unsigned short* vbase = vtb + head_base + jt * 32;
#pragma unroll
    for (int it = 0; it < 4; it++) {
      int base_slot = wave * 256 + it * 64;
      int sigma = base_slot + lane;
      int s = sigma >> 4, gk = (sigma & 15) ^ (s & 7);
      load_lds16(kbase + (size_t)s * DD + gk * 8, &Ks[buf][base_slot * 8]);
      int d = sigma >> 2, gv = (sigma & 3) ^ ((d >> 1) & 3);
      load_lds16(vbase + (size_t)d * TT + gv * 8, &Vts[buf][base_slot * 8]);
    }
  };

  stage(jt0, 0);
  __syncthreads();

  for (int it = 0; it < niter; it++) {
    const int jt = jt0 + it;
    const int buf = it & 1;
    if (it + 1 < niter) stage(jt + 1, buf ^ 1);

    if (jt * 32 <= m0 + 31) {        // wave not fully masked (uniform branch)
      const int j0 = jt * 32;
      f32x4 st[2][2];
#pragma unroll
      for (int qs = 0; qs < 2; qs++) { st[qs][0] = (f32x4){0,0,0,0}; st[qs][1] = (f32x4){0,0,0,0}; }
#pragma unroll
      for (int kb = 0; kb < 4; kb++) {
        int g = 4 * kb + quad;
        v8bf a0 = *(const v8bf*)&Ks[buf][(16 * fr + (g ^ (fr & 7))) * 8];
        v8bf a1 = *(const v8bf*)&Ks[buf][(16 * (fr + 16) + (g ^ (fr & 7))) * 8];
        st[0][0] = __builtin_amdgcn_mfma_f32_16x16x32_bf16(a0, qf[0][kb], st[0][0], 0, 0, 0);
        st[0][1] = __builtin_amdgcn_mfma_f32_16x16x32_bf16(a1, qf[0][kb], st[0][1], 0, 0, 0);
        st[1][0] = __builtin_amdgcn_mfma_f32_16x16x32_bf16(a0, qf[1][kb], st[1][0], 0, 0, 0);
        st[1][1] = __builtin_amdgcn_mfma_f32_16x16x32_bf16(a1, qf[1][kb], st[1][1], 0, 0, 0);
      }

#pragma unroll
      for (int qs = 0; qs < 2; qs++) {
        const int qrow = m0 + qs * 16 + fr;
        float p[8]; float ls = 0.f;
#pragma unroll
        for (int r = 0; r < 4; r++) {
          int c0 = j0 + quad * 4 + r;
          p[r]     = (c0      <= qrow) ? exp2f(st[qs][0][r] * QKSCALE) : 0.f;
          p[4 + r] = (c0 + 16 <= qrow) ? exp2f(st[qs][1][r] * QKSCALE) : 0.f;
          ls += p[r] + p[4 + r];
        }
        lsum[qs] += ls;
        ushort4 w0 = { f2b(p[0]), f2b(p[1]), f2b(p[2]), f2b(p[3]) };
        ushort4 w1 = { f2b(p[4]), f2b(p[5]), f2b(p[6]), f2b(p[7]) };
        *(ushort4*)&Ps[wave][qs * 16 + fr][quad * 4] = w0;
        *(ushort4*)&Ps[wave][qs * 16 + fr][16 + quad * 4] = w1;
      }

      v8bf pa0 = *(const v8bf*)&Ps[wave][fr][quad * 8];
      v8bf pa1 = *(const v8bf*)&Ps[wave][16 + fr][quad * 8];
#pragma unroll
      for (int nt2 = 0; nt2 < 8; nt2++) {
        int d = nt2 * 16 + fr;
        v8bf vb = *(const v8bf*)&Vts[buf][(4 * d + (quad ^ ((d >> 1) & 3))) * 8];
        oacc[0][nt2] = __builtin_amdgcn_mfma_f32_16x16x32_bf16(pa0, vb, oacc[0][nt2], 0, 0, 0);
        oacc[1][nt2] = __builtin_amdgcn_mfma_f32_16x16x32_bf16(pa1, vb, oacc[1][nt2], 0, 0, 0);
      }
    }
    __syncthreads();
  }

  // epilogue: write fp32 partial O + l (no divide; combine kernel finishes)
  float* Oc = Opart + (size_t)chunk * (BB * HH * TT * DD) + head_base;
#pragma unroll
  for (int qs = 0; qs < 2; qs++) {
    float l = lsum[qs];
    l += __shfl_xor(l, 16);
    l += __shfl_xor(l, 32);
    if (quad == 0)
      lpart[chunk * (BB * HH * TT) + bh * TT + m0 + qs * 16 + fr] = l;
#pragma unroll
    for (int nt2 = 0; nt2 < 8; nt2++)
#pragma unroll
      for (int r = 0; r < 4; r++)
        Oc[(size_t)(m0 + qs * 16 + quad * 4 + r) * DD + nt2 * 16 + fr] = oacc[qs][nt2][r];
  }
}

// ---------------- combine: yb = (O0+O1)/(l0+l1), bf16 [bt][C] ----------------
__global__ __launch_bounds__(256) void combine_kernel(const float* __restrict__ Opart,
                                                      const float* __restrict__ lpart,
                                                      unsigned short* __restrict__ yb) {
  int idx = blockIdx.x * 256 + threadIdx.x;   // 1,572,864 threads, float4 each
  int row = idx >> 5;                          // bh*2048 + t
  int dg = (idx & 31) * 4;
  float4 o0 = *(const float4*)&Opart[(size_t)row * DD + dg];
  float4 o1 = *(const float4*)&Opart[(size_t)(BB * HH * TT) * DD + (size_t)row * DD + dg];
  float linv = 1.f / (lpart[row] + lpart[BB * HH * TT + row]);
  int bh = row >> 11, t = row & 2047;
  int b = bh / HH, h = bh % HH;
  ushort4 u = { f2b((o0.x + o1.x) * linv), f2b((o0.y + o1.y) * linv),
                f2b((o0.z + o1.z) * linv), f2b((o0.w + o1.w) * linv) };
  *(ushort4*)&yb[((size_t)(b * TT + t)) * CC + h * DD + dg] = u;
}

// ---------------- launch ----------------
extern "C" void kernel_launch(void* const* d_in, const int* in_sizes, int n_in,
                              void* d_out, int out_size, void* d_ws, size_t ws_size,
                              hipStream_t stream) {
  const float* x     = (const float*)d_in[0];
  const float* cosb  = (const float*)d_in[1];
  const float* sinb  = (const float*)d_in[2];
  const float* wq    = (const float*)d_in[3];
  const float* wk    = (const float*)d_in[4];
  const float* wv    = (const float*)d_in[5];
  const float* wproj = (const float*)d_in[6];
  float* out = (float*)d_out;

  // workspace layout (117,964,800 B):
  //   0         : q fp32 (25.17M)  -> dead after rope -> Opart chunk0
  //   25165824  : kk fp32 (25.17M) -> dead after rope -> Opart chunk1
  //   50331648  : yb bf16 (12.58M)  [combine out, wproj in]
  //   62914560  : v_t bf16 [bh][d][t] (12.58M)  [gemm_qkv out]
  //   75497472  : q_t bf16 [bh][t][d] (12.58M)
  //   88080384  : k_t bf16 (12.58M)
  //   100663296 : xb bf16 (12.58M) -> dead after gemm_qkv -> lpart (393K)
  //   113246208 : wb bf16 4x589824 elems (4.72M)
  char* w = (char*)d_ws;
  float* q     = (float*)(w);
  float* kk    = (float*)(w + 25165824);
  float* Opart = (float*)(w);
  unsigned short* yb  = (unsigned short*)(w + 50331648);
  unsigned short* v_t = (unsigned short*)(w + 62914560);
  unsigned short* q_t = (unsigned short*)(w + 75497472);
  unsigned short* k_t = (unsigned short*)(w + 88080384);
  unsigned short* xb  = (unsigned short*)(w + 100663296);
  float* lpart        = (float*)(w + 100663296);   // alias xb (dead after gemm_qkv)
  unsigned short* wb  = (unsigned short*)(w + 113246208);

  const int nx4 = BT * CC / 4;   // 1572864

  cvt_f2b_kernel<<<nx4 / 256, 256, 0, stream>>>(x, xb, nx4);
  cvt_w4_kernel<<<2304, 256, 0, stream>>>(wq, wk, wv, wproj, wb);

  gemm_qkv<<<dim3(BT / 128, 3 * HH), 256, 0, stream>>>(xb, wb, q, kk, v_t);

  int nvec = BT * HH;  // 49152
  rope_norm_kernel<<<nvec / 4, 256, 0, stream>>>(q, q_t, cosb, sinb);
  rope_norm_kernel<<<nvec / 4, 256, 0, stream>>>(kk, k_t, cosb, sinb);

  attn_mfma<<<1536, 128, 0, stream>>>(q_t, k_t, v_t, Opart, lpart);
  combine_kernel<<<6144, 256, 0, stream>>>(Opart, lpart, yb);

  gemm_w64<<<dim3(BT / 64, CC / 128), 256, 0, stream>>>(yb, wb + 3 * 589824, out);
}